// Round 1
// baseline (1067.291 us; speedup 1.0000x reference)
//
#include <hip/hip_runtime.h>

// Problem constants
#define B_    16
#define T_    8
#define K_    64
#define COUT  128
#define CIN   128
#define KH    5
#define KW    5
#define H_    64
#define W_    64
#define PAD   2
#define WSZ   (COUT*CIN*KH*KW)   // 409600 elements per k (and per b for lp)

// ---------------------------------------------------------------------------
// Kernel 1: coef[b,k] = (1/T) * sum_t tf[b,t,k]     (16x64 = 1024 outputs)
// ---------------------------------------------------------------------------
__global__ void coef_kernel(const float* __restrict__ tf, float* __restrict__ coef) {
    int gid = blockIdx.x * 256 + threadIdx.x;
    if (gid < B_ * K_) {
        int b = gid >> 6;
        int k = gid & 63;
        float s = 0.f;
#pragma unroll
        for (int t = 0; t < T_; ++t) s += tf[(b * T_ + t) * K_ + k];
        coef[gid] = s * (1.0f / T_);
    }
}

// ---------------------------------------------------------------------------
// Kernel 2: lp[b, idx] = sum_k coef[b,k] * Wbank[k, idx],  idx in [0, 409600)
// Each thread: 4 consecutive idx (float4), all 16 b accumulated in registers.
// Wbank read exactly once (104.9 MB), lp written once (26.2 MB) -> HBM-bound.
// ---------------------------------------------------------------------------
__global__ __launch_bounds__(256) void lp_kernel(const float* __restrict__ Wb,
                                                 const float* __restrict__ coef,
                                                 float* __restrict__ lp) {
    __shared__ float cs[B_ * K_];
    int tid = threadIdx.x;
    for (int i = tid; i < B_ * K_; i += 256) cs[i] = coef[i];
    __syncthreads();

    int base = (blockIdx.x * 256 + tid) * 4;   // < 409600

    float4 acc[B_];
#pragma unroll
    for (int b = 0; b < B_; ++b) acc[b] = make_float4(0.f, 0.f, 0.f, 0.f);

    for (int k = 0; k < K_; ++k) {
        const float4 wv = *(const float4*)(Wb + (size_t)k * WSZ + base);
#pragma unroll
        for (int b = 0; b < B_; ++b) {
            float c = cs[b * K_ + k];
            acc[b].x += c * wv.x;
            acc[b].y += c * wv.y;
            acc[b].z += c * wv.z;
            acc[b].w += c * wv.w;
        }
    }
#pragma unroll
    for (int b = 0; b < B_; ++b)
        *(float4*)(lp + (size_t)b * WSZ + base) = acc[b];
}

// ---------------------------------------------------------------------------
// Kernel 3: direct conv, fp32.
// grid = 16 b * 16 o-groups * 8 h-tiles = 2048 blocks, 256 threads.
// Block computes 8 output channels x 8 rows x 64 cols.
// Thread: one o, 4x4 pixel patch. Per input channel c:
//   - stage x halo tile 12x68 (rows h0-2..h0+9, cols -2..65) in LDS
//   - stage 8x25 weights in LDS
//   - thread caches its 8x8 x-patch in registers (16x reuse), 400 FMA/c.
// ---------------------------------------------------------------------------
__global__ __launch_bounds__(256) void conv_kernel(const float* __restrict__ x,
                                                   const float* __restrict__ lp,
                                                   float* __restrict__ out) {
    int bid = blockIdx.x;
    int ht = bid & 7;            // h tile
    int og = (bid >> 3) & 15;    // o group
    int b  = bid >> 7;
    int h0 = ht * 8;
    int o0 = og * 8;

    __shared__ __align__(16) float xt[12 * 68];
    __shared__ __align__(16) float wt[8 * 25];

    int tid = threadIdx.x;
    int to = tid >> 5;           // 0..7 -> output channel within group
    int ts = tid & 31;
    int tw = ts & 15;            // 0..15 -> w0 = 4*tw
    int th = ts >> 4;            // 0..1  -> hh = 4*th
    int w0 = tw * 4;
    int hh = th * 4;
    int o  = o0 + to;

    float acc[16];
#pragma unroll
    for (int i = 0; i < 16; ++i) acc[i] = 0.f;

    const float* xb  = x  + (size_t)b * CIN * H_ * W_;
    const float* lpb = lp + (size_t)b * WSZ;

    for (int c = 0; c < CIN; ++c) {
        __syncthreads();   // protect LDS from previous iteration's readers
        const float* xc = xb + c * H_ * W_;
        // stage x halo tile (816 elements)
        for (int e = tid; e < 12 * 68; e += 256) {
            int r  = e / 68;
            int cc = e - r * 68;
            int gr = h0 - 2 + r;
            int gc = cc - 2;
            float v = 0.f;
            if (gr >= 0 && gr < H_ && gc >= 0 && gc < W_) v = xc[gr * W_ + gc];
            xt[e] = v;
        }
        // stage 8x25 weights
        if (tid < 200) {
            int oo = tid / 25;
            int q  = tid - oo * 25;
            wt[tid] = lpb[((o0 + oo) * CIN + c) * 25 + q];
        }
        __syncthreads();

        // register-cache 8x8 x patch
        float xp[8][8];
#pragma unroll
        for (int r = 0; r < 8; ++r) {
            float4 v0 = *(const float4*)&xt[(hh + r) * 68 + w0];
            float4 v1 = *(const float4*)&xt[(hh + r) * 68 + w0 + 4];
            xp[r][0] = v0.x; xp[r][1] = v0.y; xp[r][2] = v0.z; xp[r][3] = v0.w;
            xp[r][4] = v1.x; xp[r][5] = v1.y; xp[r][6] = v1.z; xp[r][7] = v1.w;
        }

        const float* wrow = &wt[to * 25];
#pragma unroll
        for (int i = 0; i < KH; ++i) {
#pragma unroll
            for (int j = 0; j < KW; ++j) {
                float wv = wrow[i * 5 + j];
#pragma unroll
                for (int py = 0; py < 4; ++py) {
#pragma unroll
                    for (int px = 0; px < 4; ++px) {
                        acc[py * 4 + px] += wv * xp[py + i][px + j];
                    }
                }
            }
        }
    }

    // store 4x4 patch
#pragma unroll
    for (int py = 0; py < 4; ++py) {
        int h = h0 + hh + py;
        float4 v = make_float4(acc[py * 4 + 0], acc[py * 4 + 1],
                               acc[py * 4 + 2], acc[py * 4 + 3]);
        *(float4*)&out[(((size_t)b * COUT + o) * H_ + h) * W_ + w0] = v;
    }
}

// ---------------------------------------------------------------------------
extern "C" void kernel_launch(void* const* d_in, const int* in_sizes, int n_in,
                              void* d_out, int out_size, void* d_ws, size_t ws_size,
                              hipStream_t stream) {
    const float* x  = (const float*)d_in[0];   // (16,128,64,64)
    const float* tf = (const float*)d_in[1];   // (16,8,64)
    const float* Wb = (const float*)d_in[2];   // (64,128,128,5,5)
    float* out = (float*)d_out;                // (16,128,64,64) fp32

    // workspace layout: lp (16*409600 f32) then coef (1024 f32) = ~26.2 MB
    float* lp   = (float*)d_ws;
    float* coef = lp + (size_t)B_ * WSZ;

    coef_kernel<<<4, 256, 0, stream>>>(tf, coef);
    lp_kernel<<<WSZ / (256 * 4), 256, 0, stream>>>(Wb, coef, lp);
    conv_kernel<<<B_ * 16 * 8, 256, 0, stream>>>(x, lp, out);
}

// Round 2
// 298.985 us; speedup vs baseline: 3.5697x; 3.5697x over previous
//
#include <hip/hip_runtime.h>

#define B_    16
#define T_    8
#define K_    64
#define COUT  128
#define CIN   128
#define H_    64
#define W_    64
#define WSZ   (COUT*CIN*5*5)        // 409600 per-k (and per-b) weight elems

typedef __bf16 bf16x8 __attribute__((ext_vector_type(8)));
typedef float  f32x4  __attribute__((ext_vector_type(4)));

static __device__ __forceinline__ unsigned short f2bf(float f) {
    unsigned int u = __builtin_bit_cast(unsigned int, f);
    unsigned int r = (u + 0x7FFFu + ((u >> 16) & 1u)) >> 16;
    return (unsigned short)r;
}

// ---------------------------------------------------------------------------
// Kernel 1 (fused coef + weight-gen + repack):
//   lpT[b][tap][o][c] (bf16) = sum_k mean_t(tf[b,t,k]) * Wb[k,o,c,tap]
// Grid: 128 o * 4 c-chunks = 512 blocks. Wb read coalesced exactly once.
// Epilogue transposes [c][tap] -> [tap][c] through LDS for coalesced writes.
// ---------------------------------------------------------------------------
__global__ __launch_bounds__(256) void lp_kernel(const float* __restrict__ Wb,
                                                 const float* __restrict__ tf,
                                                 unsigned short* __restrict__ lpT) {
    int o = blockIdx.x >> 2;      // 0..127
    int s = blockIdx.x & 3;       // c chunk: c in [32s, 32s+32)
    int tid = threadIdx.x;

    __shared__ float cs[B_ * K_];                  // 4 KB
    __shared__ unsigned short lt[B_ * 800];        // 25.6 KB

    // coef[b,k] = mean_t tf[b,t,k]
    {
        int idx = tid;
#pragma unroll
        for (int r = 0; r < 4; ++r, idx += 256) {
            int b = idx >> 6, k = idx & 63;
            float sum = 0.f;
#pragma unroll
            for (int t = 0; t < T_; ++t) sum += tf[(b * T_ + t) * K_ + k];
            cs[idx] = sum * 0.125f;
        }
    }
    __syncthreads();

    if (tid < 200) {
        // this thread: 4 consecutive flat elems of [c][tap] within chunk s
        int base = o * 3200 + s * 800 + tid * 4;
        float4 acc[B_];
#pragma unroll
        for (int b = 0; b < B_; ++b) acc[b] = make_float4(0.f, 0.f, 0.f, 0.f);

        for (int k = 0; k < K_; ++k) {
            const float4 wv = *(const float4*)(Wb + (size_t)k * WSZ + base);
#pragma unroll
            for (int b = 0; b < B_; ++b) {
                float c = cs[b * K_ + k];
                acc[b].x += c * wv.x;
                acc[b].y += c * wv.y;
                acc[b].z += c * wv.z;
                acc[b].w += c * wv.w;
            }
        }
        unsigned int* ltw = (unsigned int*)lt;
#pragma unroll
        for (int b = 0; b < B_; ++b) {
            unsigned int p0 = f2bf(acc[b].x) | ((unsigned int)f2bf(acc[b].y) << 16);
            unsigned int p1 = f2bf(acc[b].z) | ((unsigned int)f2bf(acc[b].w) << 16);
            ltw[b * 400 + tid * 2]     = p0;
            ltw[b * 400 + tid * 2 + 1] = p1;
        }
    }
    __syncthreads();

    // writeout: 16 b * 25 tap * 16 c-pairs = 6400 u32 = 25 * 256
    unsigned int* outw = (unsigned int*)lpT;
#pragma unroll
    for (int it = 0; it < 25; ++it) {
        int item = tid + (it << 8);
        int bq  = item / 400;
        int rem = item - bq * 400;
        int tap = rem >> 4;
        int cp  = rem & 15;
        unsigned int lo = lt[bq * 800 + cp * 50 + tap];
        unsigned int hi = lt[bq * 800 + cp * 50 + 25 + tap];
        unsigned int v = lo | (hi << 16);
        size_t us = (((size_t)(bq * 25 + tap) * COUT + o) * CIN + s * 32);
        outw[(us >> 1) + cp] = v;
    }
}

// ---------------------------------------------------------------------------
// Kernel 2: x (fp32 NCHW) -> xT bf16 [b][h][w][c]  (MFMA B-operand layout)
// Grid: 16 b * 64 h = 1024 blocks. LDS tile transpose, coalesced both sides.
// ---------------------------------------------------------------------------
__global__ __launch_bounds__(256) void xtrans(const float* __restrict__ x,
                                              unsigned short* __restrict__ xT) {
    int bid = blockIdx.x;
    int b = bid >> 6, h = bid & 63;
    __shared__ __align__(16) unsigned short ls[64 * 136];   // pad c-stride 128->136

    int tid = threadIdx.x;
    int w = tid & 63, cb = tid >> 6;          // cb: 4 groups of 32 c
    const float* xp = x + (((size_t)(b * CIN + cb * 32) * H_ + h) * W_) + w;
#pragma unroll
    for (int p = 0; p < 16; ++p) {
        float f0 = xp[(size_t)(2 * p) * (H_ * W_)];
        float f1 = xp[(size_t)(2 * p + 1) * (H_ * W_)];
        unsigned int v = f2bf(f0) | ((unsigned int)f2bf(f1) << 16);
        *(unsigned int*)&ls[w * 136 + cb * 32 + 2 * p] = v;
    }
    __syncthreads();

    unsigned short* xTb = xT + ((size_t)(b * 64 + h) * 64) * 128;
    int chunk = tid & 15, wr = tid >> 4;
#pragma unroll
    for (int pass = 0; pass < 4; ++pass) {
        int ww = pass * 16 + wr;
        uint4 v = *(const uint4*)&ls[ww * 136 + chunk * 8];
        *(uint4*)&xTb[ww * 128 + chunk * 8] = v;
    }
}

// ---------------------------------------------------------------------------
// Kernel 3: conv as 25 shifted GEMMs, bf16 MFMA 16x16x32, fp32 accum.
// Grid: 16 b * 32 row-pairs = 512 blocks, 256 thr (4 waves).
// Block tile: M=128 (o) x N=128 (2 rows x 64 w). Wave: 64x64 (4mt x 4nt).
// Per c-chunk (32 ch): stage x rows (6x68, pad-40 c-stride) once; loop 25 taps,
// a-frags direct from L2 (lpT), b-frags from LDS; 1-tap software pipeline.
// ---------------------------------------------------------------------------
__global__ __launch_bounds__(256) void conv_mfma(const unsigned short* __restrict__ xT,
                                                 const unsigned short* __restrict__ lpT,
                                                 float* __restrict__ out) {
    int bid = blockIdx.x;
    int b  = bid >> 5;
    int h0 = (bid & 31) << 1;

    int tid  = threadIdx.x;
    int lane = tid & 63, wid = tid >> 6;
    int wm = wid & 1, wn = wid >> 1;          // wm: o-half, wn: output row
    int n16 = lane & 15, quad = lane >> 4;

    __shared__ __align__(16) unsigned short xs[408 * 40];   // 32640 B

    f32x4 acc[4][4];
#pragma unroll
    for (int mt = 0; mt < 4; ++mt)
#pragma unroll
        for (int nt = 0; nt < 4; ++nt) acc[mt][nt] = (f32x4){0.f, 0.f, 0.f, 0.f};

    const unsigned short* xTb = xT + (size_t)b * (64 * 64 * 128);
    const unsigned short* lpA = lpT + (size_t)b * 409600
                              + ((size_t)(wm * 64 + n16)) * 128 + quad * 8;

#define LOAD_FRAGS(A, Bf, tap) do {                                          \
    int i_ = (tap) / 5, j_ = (tap) - 5 * i_;                                 \
    const unsigned short* ap_ = lpA + (tap) * 16384 + kcOff;                 \
    A[0] = *(const bf16x8*)(ap_);                                            \
    A[1] = *(const bf16x8*)(ap_ + 2048);                                     \
    A[2] = *(const bf16x8*)(ap_ + 4096);                                     \
    A[3] = *(const bf16x8*)(ap_ + 6144);                                     \
    const unsigned short* bp_ = &xs[(((wn + i_) * 68) + n16 + j_) * 40 + quad * 8]; \
    Bf[0] = *(const bf16x8*)(bp_);                                           \
    Bf[1] = *(const bf16x8*)(bp_ + 16 * 40);                                 \
    Bf[2] = *(const bf16x8*)(bp_ + 32 * 40);                                 \
    Bf[3] = *(const bf16x8*)(bp_ + 48 * 40);                                 \
} while (0)

#define DO_MFMA(A, Bf) do {                                                  \
    _Pragma("unroll") for (int mt = 0; mt < 4; ++mt)                         \
    _Pragma("unroll") for (int nt = 0; nt < 4; ++nt)                         \
        acc[mt][nt] = __builtin_amdgcn_mfma_f32_16x16x32_bf16(               \
            A[mt], Bf[nt], acc[mt][nt], 0, 0, 0);                            \
} while (0)

    for (int kc = 0; kc < 4; ++kc) {
        int kcOff = kc * 32;
        __syncthreads();                       // previous chunk's readers done
        // stage x rows h0-2 .. h0+3, cols -2..65 (zeros outside), 32 channels
        for (int sIdx = tid; sIdx < 408; sIdx += 256) {
            unsigned int su = (unsigned int)sIdx;
            int rr = su / 68u;
            int ww = su - rr * 68u;
            int gr = h0 - 2 + rr, gw = ww - 2;
            uint4* dst = (uint4*)&xs[sIdx * 40];
            if ((unsigned)gr < 64u && (unsigned)gw < 64u) {
                const uint4* src = (const uint4*)(xTb + (((size_t)gr * 64 + gw) * 128 + kcOff));
                dst[0] = src[0]; dst[1] = src[1]; dst[2] = src[2]; dst[3] = src[3];
            } else {
                uint4 z = {0u, 0u, 0u, 0u};
                dst[0] = z; dst[1] = z; dst[2] = z; dst[3] = z;
            }
        }
        __syncthreads();

        bf16x8 a0[4], b0[4], a1[4], b1[4];
        LOAD_FRAGS(a0, b0, 0);
        for (int t = 0; t < 24; t += 2) {
            LOAD_FRAGS(a1, b1, t + 1);
            DO_MFMA(a0, b0);
            LOAD_FRAGS(a0, b0, t + 2);
            DO_MFMA(a1, b1);
        }
        DO_MFMA(a0, b0);                       // tap 24
    }

    // epilogue: D row (o) = quad*4 + reg, D col (pixel) = lane&15
    float* outb = out + (size_t)b * (COUT * H_ * W_) + (size_t)(h0 + wn) * W_;
#pragma unroll
    for (int mt = 0; mt < 4; ++mt) {
#pragma unroll
        for (int nt = 0; nt < 4; ++nt) {
#pragma unroll
            for (int r = 0; r < 4; ++r) {
                int o = wm * 64 + mt * 16 + quad * 4 + r;
                int w = nt * 16 + n16;
                outb[(size_t)o * (H_ * W_) + w] = acc[mt][nt][r];
            }
        }
    }
#undef LOAD_FRAGS
#undef DO_MFMA
}

// ---------------------------------------------------------------------------
extern "C" void kernel_launch(void* const* d_in, const int* in_sizes, int n_in,
                              void* d_out, int out_size, void* d_ws, size_t ws_size,
                              hipStream_t stream) {
    const float* x  = (const float*)d_in[0];   // (16,128,64,64)
    const float* tf = (const float*)d_in[1];   // (16,8,64)
    const float* Wb = (const float*)d_in[2];   // (64,128,128,5,5)
    float* out = (float*)d_out;                // (16,128,64,64) fp32

    // ws: lpT bf16 [16][25][128][128] = 13.1 MB, then xT bf16 [16][64][64][128] = 16.8 MB
    unsigned short* lpT = (unsigned short*)d_ws;
    unsigned short* xT  = lpT + (size_t)B_ * 25 * COUT * CIN;

    lp_kernel<<<512, 256, 0, stream>>>(Wb, tf, lpT);
    xtrans  <<<1024, 256, 0, stream>>>(x, xT);
    conv_mfma<<<512, 256, 0, stream>>>(xT, lpT, out);
}

// Round 3
// 240.860 us; speedup vs baseline: 4.4312x; 1.2413x over previous
//
#include <hip/hip_runtime.h>

#define B_    16
#define T_    8
#define K_    64
#define COUT  128
#define CIN   128
#define H_    64
#define W_    64
#define WSZ   (COUT*CIN*5*5)        // 409600 per-k (and per-b) weight elems

typedef __bf16 bf16x8 __attribute__((ext_vector_type(8)));
typedef float  f32x4  __attribute__((ext_vector_type(4)));

static __device__ __forceinline__ unsigned short f2bf(float f) {
    unsigned int u = __builtin_bit_cast(unsigned int, f);
    unsigned int r = (u + 0x7FFFu + ((u >> 16) & 1u)) >> 16;
    return (unsigned short)r;
}

// ---------------------------------------------------------------------------
// Kernel 1 (fused coef + weight-gen + fragment repack):
//   value(b,o,c,tap) = sum_k mean_t(tf[b,t,k]) * Wb[k,o,c,tap]
// written in MFMA-A fragment order:
//   lpF[b][tap][kc(4)][wm(2)][mt(4)][lane(64)][j(8)]  (bf16)
//   where o = wm*64 + mt*16 + (lane&15), c = kc*32 + (lane>>4)*8 + j
// Grid: 128 o * 4 c-chunks = 512 blocks. Wb read coalesced exactly once.
// ---------------------------------------------------------------------------
__global__ __launch_bounds__(256) void lp_kernel(const float* __restrict__ Wb,
                                                 const float* __restrict__ tf,
                                                 unsigned short* __restrict__ lpF) {
    int o = blockIdx.x >> 2;      // 0..127
    int s = blockIdx.x & 3;       // c chunk: c in [32s, 32s+32)
    int tid = threadIdx.x;

    __shared__ float cs[B_ * K_];                  // 4 KB
    __shared__ unsigned short lt[B_ * 800];        // 25.6 KB: [b][c_local*25+tap]

    // coef[b,k] = mean_t tf[b,t,k]
    {
        int idx = tid;
#pragma unroll
        for (int r = 0; r < 4; ++r, idx += 256) {
            int b = idx >> 6, k = idx & 63;
            float sum = 0.f;
#pragma unroll
            for (int t = 0; t < T_; ++t) sum += tf[(b * T_ + t) * K_ + k];
            cs[idx] = sum * 0.125f;
        }
    }
    __syncthreads();

    if (tid < 200) {
        // this thread: 4 consecutive flat elems of [c_local][tap] within chunk s
        int base = o * 3200 + s * 800 + tid * 4;
        float4 acc[B_];
#pragma unroll
        for (int b = 0; b < B_; ++b) acc[b] = make_float4(0.f, 0.f, 0.f, 0.f);

        float4 cur = *(const float4*)(Wb + base);
        for (int k = 0; k < K_; ++k) {
            float4 nxt = cur;
            if (k < K_ - 1)
                nxt = *(const float4*)(Wb + (size_t)(k + 1) * WSZ + base);
#pragma unroll
            for (int b = 0; b < B_; ++b) {
                float c = cs[b * K_ + k];
                acc[b].x += c * cur.x;
                acc[b].y += c * cur.y;
                acc[b].z += c * cur.z;
                acc[b].w += c * cur.w;
            }
            cur = nxt;
        }
        unsigned int* ltw = (unsigned int*)lt;
#pragma unroll
        for (int b = 0; b < B_; ++b) {
            unsigned int p0 = f2bf(acc[b].x) | ((unsigned int)f2bf(acc[b].y) << 16);
            unsigned int p1 = f2bf(acc[b].z) | ((unsigned int)f2bf(acc[b].w) << 16);
            ltw[b * 400 + tid * 2]     = p0;
            ltw[b * 400 + tid * 2 + 1] = p1;
        }
    }
    __syncthreads();

    // writeout in fragment order. This block owns one o and c-chunk s:
    //   wm = o>>6, mt = (o>>4)&3, n16 = o&15  (fixed); quad = 0..3 varies.
    // items: 16 b * 25 tap * 4 quad = 1600, each a 16B (8-short) store.
    int wm = o >> 6, mt = (o >> 4) & 3, n16 = o & 15;
    for (int it = tid; it < 1600; it += 256) {
        int b = it / 100;
        int r = it - b * 100;
        int tap = r >> 2;
        int quad = r & 3;
        unsigned short v[8];
#pragma unroll
        for (int j = 0; j < 8; ++j)
            v[j] = lt[b * 800 + (quad * 8 + j) * 25 + tap];
        size_t off = (size_t)b * 409600
                   + (size_t)((((tap * 4 + s) * 2 + wm) * 4 + mt) * 512
                              + quad * 128 + n16 * 8);
        *(uint4*)(lpF + off) = *(const uint4*)v;
    }
}

// ---------------------------------------------------------------------------
// Kernel 2: x (fp32 NCHW) -> xT bf16 [b][h][w][c]  (MFMA B-operand layout)
// ---------------------------------------------------------------------------
__global__ __launch_bounds__(256) void xtrans(const float* __restrict__ x,
                                              unsigned short* __restrict__ xT) {
    int bid = blockIdx.x;
    int b = bid >> 6, h = bid & 63;
    __shared__ __align__(16) unsigned short ls[64 * 136];   // pad c-stride 128->136

    int tid = threadIdx.x;
    int w = tid & 63, cb = tid >> 6;          // cb: 4 groups of 32 c
    const float* xp = x + (((size_t)(b * CIN + cb * 32) * H_ + h) * W_) + w;
#pragma unroll
    for (int p = 0; p < 16; ++p) {
        float f0 = xp[(size_t)(2 * p) * (H_ * W_)];
        float f1 = xp[(size_t)(2 * p + 1) * (H_ * W_)];
        unsigned int v = f2bf(f0) | ((unsigned int)f2bf(f1) << 16);
        *(unsigned int*)&ls[w * 136 + cb * 32 + 2 * p] = v;
    }
    __syncthreads();

    unsigned short* xTb = xT + ((size_t)(b * 64 + h) * 64) * 128;
    int chunk = tid & 15, wr = tid >> 4;
#pragma unroll
    for (int pass = 0; pass < 4; ++pass) {
        int ww = pass * 16 + wr;
        uint4 v = *(const uint4*)&ls[ww * 136 + chunk * 8];
        *(uint4*)&xTb[ww * 128 + chunk * 8] = v;
    }
}

// ---------------------------------------------------------------------------
// Kernel 3: conv as 25 shifted GEMMs, bf16 MFMA 16x16x32, fp32 accum.
// Grid: 512 blocks, XCD-swizzled: b = (bid&7)|((bid>>3)&1)<<3 so each XCD's
// L2 holds exactly 2 batches' lpF (2x819KB) + xT (2x1.05MB) = 3.7MB hot set.
// Block tile: M=128 (o) x N=128 (2 rows x 64 w). Wave: 64x64 (4mt x 4nt).
// A-frags: lane-contiguous 1KB coalesced loads from L2-resident lpF.
// ---------------------------------------------------------------------------
__global__ __launch_bounds__(256) void conv_mfma(const unsigned short* __restrict__ xT,
                                                 const unsigned short* __restrict__ lpF,
                                                 float* __restrict__ out) {
    int bid = blockIdx.x;
    int b  = (bid & 7) | (((bid >> 3) & 1) << 3);   // XCD-local batch
    int h0 = (bid >> 4) << 1;                       // row pair

    int tid  = threadIdx.x;
    int lane = tid & 63, wid = tid >> 6;
    int wm = wid & 1, wn = wid >> 1;          // wm: o-half, wn: output row
    int n16 = lane & 15, quad = lane >> 4;

    __shared__ __align__(16) unsigned short xs[408 * 40];   // 32640 B

    f32x4 acc[4][4];
#pragma unroll
    for (int mt = 0; mt < 4; ++mt)
#pragma unroll
        for (int nt = 0; nt < 4; ++nt) acc[mt][nt] = (f32x4){0.f, 0.f, 0.f, 0.f};

    const unsigned short* xTb = xT + (size_t)b * (64 * 64 * 128);
    // per-wave A base in fragment-ordered lpF
    const unsigned short* lpW = lpF + (size_t)b * 409600 + wm * 2048 + lane * 8;

#define LOAD_FRAGS(A, Bf, tap) do {                                          \
    int i_ = (tap) / 5, j_ = (tap) - 5 * i_;                                 \
    const unsigned short* ap_ = lpW + (tap) * 16384 + kc * 4096;             \
    A[0] = *(const bf16x8*)(ap_);                                            \
    A[1] = *(const bf16x8*)(ap_ + 512);                                      \
    A[2] = *(const bf16x8*)(ap_ + 1024);                                     \
    A[3] = *(const bf16x8*)(ap_ + 1536);                                     \
    const unsigned short* bp_ = &xs[(((wn + i_) * 68) + n16 + j_) * 40 + quad * 8]; \
    Bf[0] = *(const bf16x8*)(bp_);                                           \
    Bf[1] = *(const bf16x8*)(bp_ + 16 * 40);                                 \
    Bf[2] = *(const bf16x8*)(bp_ + 32 * 40);                                 \
    Bf[3] = *(const bf16x8*)(bp_ + 48 * 40);                                 \
} while (0)

#define DO_MFMA(A, Bf) do {                                                  \
    _Pragma("unroll") for (int mt = 0; mt < 4; ++mt)                         \
    _Pragma("unroll") for (int nt = 0; nt < 4; ++nt)                         \
        acc[mt][nt] = __builtin_amdgcn_mfma_f32_16x16x32_bf16(               \
            A[mt], Bf[nt], acc[mt][nt], 0, 0, 0);                            \
} while (0)

    for (int kc = 0; kc < 4; ++kc) {
        int kcOff = kc * 32;
        __syncthreads();                       // previous chunk's readers done
        // stage x rows h0-2 .. h0+3, cols -2..65 (zeros outside), 32 channels
        for (int sIdx = tid; sIdx < 408; sIdx += 256) {
            unsigned int su = (unsigned int)sIdx;
            int rr = su / 68u;
            int ww = su - rr * 68u;
            int gr = h0 - 2 + rr, gw = ww - 2;
            uint4* dst = (uint4*)&xs[sIdx * 40];
            if ((unsigned)gr < 64u && (unsigned)gw < 64u) {
                const uint4* src = (const uint4*)(xTb + (((size_t)gr * 64 + gw) * 128 + kcOff));
                dst[0] = src[0]; dst[1] = src[1]; dst[2] = src[2]; dst[3] = src[3];
            } else {
                uint4 z = {0u, 0u, 0u, 0u};
                dst[0] = z; dst[1] = z; dst[2] = z; dst[3] = z;
            }
        }
        __syncthreads();

        bf16x8 a0[4], b0[4], a1[4], b1[4];
        LOAD_FRAGS(a0, b0, 0);
        for (int t = 0; t < 24; t += 2) {
            LOAD_FRAGS(a1, b1, t + 1);
            DO_MFMA(a0, b0);
            LOAD_FRAGS(a0, b0, t + 2);
            DO_MFMA(a1, b1);
        }
        DO_MFMA(a0, b0);                       // tap 24
    }

    // epilogue: D row (o) = quad*4 + reg, D col (pixel) = lane&15
    float* outb = out + (size_t)b * (COUT * H_ * W_) + (size_t)(h0 + wn) * W_;
#pragma unroll
    for (int mt = 0; mt < 4; ++mt) {
#pragma unroll
        for (int nt = 0; nt < 4; ++nt) {
#pragma unroll
            for (int r = 0; r < 4; ++r) {
                int o = wm * 64 + mt * 16 + quad * 4 + r;
                int w = nt * 16 + n16;
                outb[(size_t)o * (H_ * W_) + w] = acc[mt][nt][r];
            }
        }
    }
#undef LOAD_FRAGS
#undef DO_MFMA
}

// ---------------------------------------------------------------------------
extern "C" void kernel_launch(void* const* d_in, const int* in_sizes, int n_in,
                              void* d_out, int out_size, void* d_ws, size_t ws_size,
                              hipStream_t stream) {
    const float* x  = (const float*)d_in[0];   // (16,128,64,64)
    const float* tf = (const float*)d_in[1];   // (16,8,64)
    const float* Wb = (const float*)d_in[2];   // (64,128,128,5,5)
    float* out = (float*)d_out;                // (16,128,64,64) fp32

    // ws: lpF bf16 fragment-ordered 16*409600 = 13.1 MB, then xT bf16 16.8 MB
    unsigned short* lpF = (unsigned short*)d_ws;
    unsigned short* xT  = lpF + (size_t)B_ * 409600;

    lp_kernel<<<512, 256, 0, stream>>>(Wb, tf, lpF);
    xtrans  <<<1024, 256, 0, stream>>>(x, xT);
    conv_mfma<<<512, 256, 0, stream>>>(xT, lpF, out);
}